// Round 1
// baseline (433.431 us; speedup 1.0000x reference)
//
#include <hip/hip_runtime.h>
#include <stdint.h>

typedef unsigned short u16;
typedef short bf16x8 __attribute__((ext_vector_type(8)));
typedef float f32x4 __attribute__((ext_vector_type(4)));

#define MB (1024L*1024L)

__device__ inline u16 f2bf(float f) {
  union { float f; unsigned u; } v; v.f = f;
  unsigned r = (v.u + 0x7FFFu + ((v.u >> 16) & 1u)) >> 16;
  return (u16)r;
}

#define GLOAD16(gptr, lptr) \
  __builtin_amdgcn_global_load_lds((__attribute__((address_space(1))) void*)(gptr), \
                                   (__attribute__((address_space(3))) void*)(lptr), 16, 0, 0)

// ---------------- transpose + convert fp32 (K,N) -> bf16 (N,K) ----------------
__global__ __launch_bounds__(256) void twconv(const float* __restrict__ W,
                                              u16* __restrict__ WT, int K, int N) {
  __shared__ float tile[32][33];
  const int nbn = N >> 5;
  const int bk = blockIdx.x / nbn;
  const int bn = blockIdx.x % nbn;
  const int tid = threadIdx.x;
  const int r = tid >> 3;
  const int c4 = (tid & 7) << 2;
  const float4 v = *(const float4*)(W + (size_t)(bk * 32 + r) * N + bn * 32 + c4);
  tile[r][c4 + 0] = v.x; tile[r][c4 + 1] = v.y;
  tile[r][c4 + 2] = v.z; tile[r][c4 + 3] = v.w;
  __syncthreads();
  ushort4 o;
  o.x = f2bf(tile[c4 + 0][r]); o.y = f2bf(tile[c4 + 1][r]);
  o.z = f2bf(tile[c4 + 2][r]); o.w = f2bf(tile[c4 + 3][r]);
  *(ushort4*)(WT + (size_t)(bn * 32 + r) * K + bk * 32 + c4) = o;
}

// ---------------- LayerNorm fp32 -> bf16, D=1024, one block per row ----------------
__global__ __launch_bounds__(256) void ln_kernel(const float* __restrict__ x,
                                                 const float* __restrict__ gamma,
                                                 const float* __restrict__ beta,
                                                 u16* __restrict__ out) {
  const int row = blockIdx.x;
  const int tid = threadIdx.x;
  const float4 v = *(const float4*)(x + (size_t)row * 1024 + tid * 4);
  float s = v.x + v.y + v.z + v.w;
  float s2 = v.x * v.x + v.y * v.y + v.z * v.z + v.w * v.w;
#pragma unroll
  for (int m = 1; m < 64; m <<= 1) {
    s += __shfl_xor(s, m, 64);
    s2 += __shfl_xor(s2, m, 64);
  }
  __shared__ float red[8];
  const int w = tid >> 6;
  if ((tid & 63) == 0) { red[w] = s; red[4 + w] = s2; }
  __syncthreads();
  s = red[0] + red[1] + red[2] + red[3];
  s2 = red[4] + red[5] + red[6] + red[7];
  const float mean = s * (1.0f / 1024.0f);
  const float var = s2 * (1.0f / 1024.0f) - mean * mean;
  const float rstd = rsqrtf(var + 1e-5f);
  const float4 g = *(const float4*)(gamma + tid * 4);
  const float4 b = *(const float4*)(beta + tid * 4);
  ushort4 o;
  o.x = f2bf(g.x * (v.x - mean) * rstd + b.x);
  o.y = f2bf(g.y * (v.y - mean) * rstd + b.y);
  o.z = f2bf(g.z * (v.z - mean) * rstd + b.z);
  o.w = f2bf(g.w * (v.w - mean) * rstd + b.w);
  *(ushort4*)(out + (size_t)row * 1024 + tid * 4) = o;
}

// ---------------- GEMM: C[M,N] = A[M,K](bf16) @ BT[N,K](bf16)^T + epilogue ----------------
// EPI 0: out bf16 = acc + bias
// EPI 1: out f32  = acc + bias + res
// EPI 2: out bf16 = gelu_erf(acc + bias)
template <int EPI>
__global__ __launch_bounds__(256, 2) void gemm_bt(const u16* __restrict__ A,
                                                  const u16* __restrict__ BT,
                                                  const float* __restrict__ bias,
                                                  const float* __restrict__ res,
                                                  void* __restrict__ outp,
                                                  int M, int N, int K) {
  __shared__ __align__(16) u16 As[128 * 32];
  __shared__ __align__(16) u16 Bs[128 * 32];
  const int nBN = N >> 7;
  const int bm = blockIdx.x / nBN;
  const int bn = blockIdx.x % nBN;
  const int tid = threadIdx.x;
  const int lane = tid & 63;
  const int wid = tid >> 6;
  const int wm = wid >> 1, wn = wid & 1;

  // fragment LDS element offsets (swizzled: chunk ^= (row>>1)&3 within 64B rows)
  int aoffs[4], boffs[4];
#pragma unroll
  for (int m = 0; m < 4; ++m) {
    int rowa = wm * 64 + m * 16 + (lane & 15);
    aoffs[m] = rowa * 32 + (((lane >> 4) ^ ((rowa >> 1) & 3)) << 3);
    int rowb = wn * 64 + m * 16 + (lane & 15);
    boffs[m] = rowb * 32 + (((lane >> 4) ^ ((rowb >> 1) & 3)) << 3);
  }

  // staging: 2 x 16B per thread per tile; LDS dest linear, global source pre-swizzled
  size_t ga[2], gb[2];
  int lo[2];
#pragma unroll
  for (int c = 0; c < 2; ++c) {
    int idx = tid + (c << 8);
    int row = idx >> 2;
    int gch = (idx & 3) ^ ((row >> 1) & 3);
    ga[c] = (size_t)(bm * 128 + row) * K + (gch << 3);
    gb[c] = (size_t)(bn * 128 + row) * K + (gch << 3);
    lo[c] = idx << 4;
  }

  f32x4 acc[4][4] = {};

  for (int k0 = 0; k0 < K; k0 += 32) {
    __syncthreads();
#pragma unroll
    for (int c = 0; c < 2; ++c) {
      GLOAD16(A + ga[c] + k0, (char*)As + lo[c]);
      GLOAD16(BT + gb[c] + k0, (char*)Bs + lo[c]);
    }
    __syncthreads();
    bf16x8 af[4], bfr[4];
#pragma unroll
    for (int m = 0; m < 4; ++m) af[m] = *(const bf16x8*)(As + aoffs[m]);
#pragma unroll
    for (int n = 0; n < 4; ++n) bfr[n] = *(const bf16x8*)(Bs + boffs[n]);
#pragma unroll
    for (int m = 0; m < 4; ++m)
#pragma unroll
      for (int n = 0; n < 4; ++n)
        acc[m][n] = __builtin_amdgcn_mfma_f32_16x16x32_bf16(af[m], bfr[n], acc[m][n], 0, 0, 0);
  }

  const int rbase = bm * 128 + wm * 64;
  const int cbase = bn * 128 + wn * 64;
#pragma unroll
  for (int m = 0; m < 4; ++m) {
#pragma unroll
    for (int n = 0; n < 4; ++n) {
      const int col = cbase + n * 16 + (lane & 15);
      const int row0 = rbase + m * 16 + ((lane >> 4) << 2);
      const float bv = bias[col];
#pragma unroll
      for (int r = 0; r < 4; ++r) {
        const int row = row0 + r;
        float v = acc[m][n][r] + bv;
        if (EPI == 1) {
          ((float*)outp)[(size_t)row * N + col] = v + res[(size_t)row * N + col];
        } else if (EPI == 2) {
          v = 0.5f * v * (1.0f + erff(v * 0.70710678118654752f));
          ((u16*)outp)[(size_t)row * N + col] = f2bf(v);
        } else {
          ((u16*)outp)[(size_t)row * N + col] = f2bf(v);
        }
      }
    }
  }
}

// ---------------- causal flash attention, T=2048, H=16, Dh=64 ----------------
// Q/K/V: bf16 (B*T, 1024) at head offset h*64. Out: bf16 (B*T, 1024).
__global__ __launch_bounds__(256, 2) void attn_kernel(const u16* __restrict__ Q,
                                                      const u16* __restrict__ K,
                                                      const u16* __restrict__ V,
                                                      u16* __restrict__ O) {
  __shared__ __align__(16) u16 Ks[64 * 64];
  __shared__ __align__(16) u16 Vt[64 * 64];
  __shared__ __align__(16) u16 Ps[64 * 64];
  const int T = 2048, LD = 1024;
  const int qt = blockIdx.x & 31;       // T/64 = 32 q-tiles
  const int bh = blockIdx.x >> 5;
  const int b = bh >> 4, h = bh & 15;
  const int tid = threadIdx.x;
  const int lane = tid & 63;
  const int w = tid >> 6;

  const u16* Qb = Q + (size_t)b * T * LD + h * 64;
  const u16* Kb = K + (size_t)b * T * LD + h * 64;
  const u16* Vb = V + (size_t)b * T * LD + h * 64;

  // Q fragments in registers (one 16-row stripe per wave)
  bf16x8 qf[2];
  const int qrow = qt * 64 + w * 16 + (lane & 15);
#pragma unroll
  for (int ks = 0; ks < 2; ++ks)
    qf[ks] = *(const bf16x8*)(Qb + (size_t)qrow * LD + ks * 32 + ((lane >> 4) << 3));

  f32x4 o[4] = {};
  float mrow[4], lrow[4];
#pragma unroll
  for (int r = 0; r < 4; ++r) { mrow[r] = -INFINITY; lrow[r] = 0.0f; }

  for (int j = 0; j <= qt; ++j) {
    __syncthreads();
    // stage K tile [64 keys][64 d], global source pre-swizzled (chunk ^= row&7)
#pragma unroll
    for (int c = 0; c < 2; ++c) {
      int idx = tid + (c << 8);
      int row = idx >> 3;
      int gch = (idx & 7) ^ (row & 7);
      GLOAD16(Kb + (size_t)(j * 64 + row) * LD + (gch << 3), (char*)Ks + (idx << 4));
    }
    // stage V transposed: Vt[d][key], swizzled
#pragma unroll
    for (int c = 0; c < 2; ++c) {
      int idx = tid + (c << 8);
      int vr = idx >> 3;
      int d0 = (idx & 7) << 3;
      bf16x8 vv = *(const bf16x8*)(Vb + (size_t)(j * 64 + vr) * LD + d0);
#pragma unroll
      for (int i = 0; i < 8; ++i) {
        int d = d0 + i;
        Vt[(d << 6) + (vr ^ ((d & 7) << 3))] = (u16)vv[i];
      }
    }
    __syncthreads();

    // S = Q @ K^T  (per wave: 16 q-rows x 64 keys)
    f32x4 s[4] = {};
#pragma unroll
    for (int n = 0; n < 4; ++n) {
#pragma unroll
      for (int ks = 0; ks < 2; ++ks) {
        int krow = n * 16 + (lane & 15);
        bf16x8 kf = *(const bf16x8*)(Ks + (krow << 6) + (((ks * 4 + (lane >> 4)) ^ (krow & 7)) << 3));
        s[n] = __builtin_amdgcn_mfma_f32_16x16x32_bf16(qf[ks], kf, s[n], 0, 0, 0);
      }
    }

    // scale + causal mask + online softmax
    float rmax[4];
#pragma unroll
    for (int r = 0; r < 4; ++r) rmax[r] = -INFINITY;
#pragma unroll
    for (int n = 0; n < 4; ++n) {
#pragma unroll
      for (int r = 0; r < 4; ++r) {
        float sv = s[n][r] * 0.125f;
        if (j == qt) {
          int key = j * 64 + n * 16 + (lane & 15);
          int qg = qt * 64 + w * 16 + ((lane >> 4) << 2) + r;
          if (key > qg) sv = -INFINITY;
        }
        s[n][r] = sv;
        rmax[r] = fmaxf(rmax[r], sv);
      }
    }
#pragma unroll
    for (int r = 0; r < 4; ++r) {
      rmax[r] = fmaxf(rmax[r], __shfl_xor(rmax[r], 1, 64));
      rmax[r] = fmaxf(rmax[r], __shfl_xor(rmax[r], 2, 64));
      rmax[r] = fmaxf(rmax[r], __shfl_xor(rmax[r], 4, 64));
      rmax[r] = fmaxf(rmax[r], __shfl_xor(rmax[r], 8, 64));
    }
    float alpha[4];
#pragma unroll
    for (int r = 0; r < 4; ++r) {
      float mn = fmaxf(mrow[r], rmax[r]);
      alpha[r] = expf(mrow[r] - mn);
      mrow[r] = mn;
    }
    float rsum[4] = {0.f, 0.f, 0.f, 0.f};
#pragma unroll
    for (int n = 0; n < 4; ++n)
#pragma unroll
      for (int r = 0; r < 4; ++r) {
        float p = expf(s[n][r] - mrow[r]);
        s[n][r] = p;
        rsum[r] += p;
      }
#pragma unroll
    for (int r = 0; r < 4; ++r) {
      rsum[r] += __shfl_xor(rsum[r], 1, 64);
      rsum[r] += __shfl_xor(rsum[r], 2, 64);
      rsum[r] += __shfl_xor(rsum[r], 4, 64);
      rsum[r] += __shfl_xor(rsum[r], 8, 64);
      lrow[r] = lrow[r] * alpha[r] + rsum[r];
#pragma unroll
      for (int df = 0; df < 4; ++df) o[df][r] *= alpha[r];
    }

    // P -> LDS (bf16, swizzled); each wave owns its 16 rows
#pragma unroll
    for (int n = 0; n < 4; ++n)
#pragma unroll
      for (int r = 0; r < 4; ++r) {
        int ql = w * 16 + ((lane >> 4) << 2) + r;
        int key = n * 16 + (lane & 15);
        Ps[(ql << 6) + (key ^ ((ql & 7) << 3))] = f2bf(s[n][r]);
      }

    // O += P @ V
#pragma unroll
    for (int ks = 0; ks < 2; ++ks) {
      int qa = w * 16 + (lane & 15);
      bf16x8 pf = *(const bf16x8*)(Ps + (qa << 6) + (((ks * 4 + (lane >> 4)) ^ (qa & 7)) << 3));
#pragma unroll
      for (int df = 0; df < 4; ++df) {
        int dr = df * 16 + (lane & 15);
        bf16x8 vf = *(const bf16x8*)(Vt + (dr << 6) + (((ks * 4 + (lane >> 4)) ^ (dr & 7)) << 3));
        o[df] = __builtin_amdgcn_mfma_f32_16x16x32_bf16(pf, vf, o[df], 0, 0, 0);
      }
    }
  }

  // epilogue: O / l
#pragma unroll
  for (int df = 0; df < 4; ++df)
#pragma unroll
    for (int r = 0; r < 4; ++r) {
      int t = qt * 64 + w * 16 + ((lane >> 4) << 2) + r;
      int dc = h * 64 + df * 16 + (lane & 15);
      O[(size_t)(b * T + t) * LD + dc] = f2bf(o[df][r] / lrow[r]);
    }
}

// ---------------- host launch ----------------
extern "C" void kernel_launch(void* const* d_in, const int* in_sizes, int n_in,
                              void* d_out, int out_size, void* d_ws, size_t ws_size,
                              hipStream_t stream) {
  const float* x      = (const float*)d_in[0];
  const float* gamma1 = (const float*)d_in[1];
  const float* beta1  = (const float*)d_in[2];
  const float* Wq     = (const float*)d_in[3];
  const float* bq     = (const float*)d_in[4];
  const float* Wk     = (const float*)d_in[5];
  const float* bk     = (const float*)d_in[6];
  const float* Wv     = (const float*)d_in[7];
  const float* bv     = (const float*)d_in[8];
  const float* Wo     = (const float*)d_in[9];
  const float* bo     = (const float*)d_in[10];
  const float* gamma2 = (const float*)d_in[11];
  const float* beta2  = (const float*)d_in[12];
  const float* W1     = (const float*)d_in[13];
  const float* b1     = (const float*)d_in[14];
  const float* W2     = (const float*)d_in[15];
  const float* b2     = (const float*)d_in[16];

  char* ws = (char*)d_ws;  // needs >= 64 MB
  u16* WqT = (u16*)(ws + 0 * MB);
  u16* WkT = (u16*)(ws + 2 * MB);
  u16* WvT = (u16*)(ws + 4 * MB);
  u16* WoT = (u16*)(ws + 6 * MB);
  u16* W1T = (u16*)(ws + 8 * MB);   // (4096,1024)
  u16* W2T = (u16*)(ws + 16 * MB);  // (1024,4096)
  u16* qb  = (u16*)(ws + 24 * MB);
  u16* kb  = (u16*)(ws + 32 * MB);
  u16* vb  = (u16*)(ws + 40 * MB);
  u16* hb  = (u16*)(ws + 24 * MB);  // reuses q/k/v region (32 MB)
  u16* xn  = (u16*)(ws + 56 * MB);  // xn1 -> attn_out -> xn2 (8 MB)
  float* x1 = (float*)d_out;        // post-attention residual, fp32

  const int M = 4096;  // B*T

  // weights -> bf16 transposed
  twconv<<<dim3(1024), dim3(256), 0, stream>>>(Wq, WqT, 1024, 1024);
  twconv<<<dim3(1024), dim3(256), 0, stream>>>(Wk, WkT, 1024, 1024);
  twconv<<<dim3(1024), dim3(256), 0, stream>>>(Wv, WvT, 1024, 1024);
  twconv<<<dim3(1024), dim3(256), 0, stream>>>(Wo, WoT, 1024, 1024);
  twconv<<<dim3(4096), dim3(256), 0, stream>>>(W1, W1T, 1024, 4096);
  twconv<<<dim3(4096), dim3(256), 0, stream>>>(W2, W2T, 4096, 1024);

  // LN1
  ln_kernel<<<dim3(M), dim3(256), 0, stream>>>(x, gamma1, beta1, xn);

  // QKV projections
  gemm_bt<0><<<dim3(256), dim3(256), 0, stream>>>(xn, WqT, bq, nullptr, qb, M, 1024, 1024);
  gemm_bt<0><<<dim3(256), dim3(256), 0, stream>>>(xn, WkT, bk, nullptr, kb, M, 1024, 1024);
  gemm_bt<0><<<dim3(256), dim3(256), 0, stream>>>(xn, WvT, bv, nullptr, vb, M, 1024, 1024);

  // attention (writes attn output into xn; xn1 no longer needed)
  attn_kernel<<<dim3(1024), dim3(256), 0, stream>>>(qb, kb, vb, xn);

  // O projection + residual -> x1 (fp32, in d_out)
  gemm_bt<1><<<dim3(256), dim3(256), 0, stream>>>(xn, WoT, bo, x, x1, M, 1024, 1024);

  // LN2
  ln_kernel<<<dim3(M), dim3(256), 0, stream>>>(x1, gamma2, beta2, xn);

  // MLP
  gemm_bt<2><<<dim3(1024), dim3(256), 0, stream>>>(xn, W1T, b1, nullptr, hb, M, 4096, 1024);
  gemm_bt<1><<<dim3(256), dim3(256), 0, stream>>>(hb, W2T, b2, x1, d_out, M, 1024, 4096);
}

// Round 2
// 319.273 us; speedup vs baseline: 1.3576x; 1.3576x over previous
//
#include <hip/hip_runtime.h>
#include <stdint.h>

typedef unsigned short u16;
typedef short bf16x8 __attribute__((ext_vector_type(8)));
typedef float f32x4 __attribute__((ext_vector_type(4)));

#define MB (1024L*1024L)

__device__ inline u16 f2bf(float f) {
  union { float f; unsigned u; } v; v.f = f;
  unsigned r = (v.u + 0x7FFFu + ((v.u >> 16) & 1u)) >> 16;
  return (u16)r;
}

#define GLOAD16(gptr, lptr) \
  __builtin_amdgcn_global_load_lds((__attribute__((address_space(1))) void*)(gptr), \
                                   (__attribute__((address_space(3))) void*)(lptr), 16, 0, 0)

// ---------------- transpose + convert fp32 (K,N) -> bf16 (N,K) ----------------
__global__ __launch_bounds__(256) void twconv(const float* __restrict__ W,
                                              u16* __restrict__ WT, int K, int N) {
  __shared__ float tile[32][33];
  const int nbn = N >> 5;
  const int bk = blockIdx.x / nbn;
  const int bn = blockIdx.x % nbn;
  const int tid = threadIdx.x;
  const int r = tid >> 3;
  const int c4 = (tid & 7) << 2;
  const float4 v = *(const float4*)(W + (size_t)(bk * 32 + r) * N + bn * 32 + c4);
  tile[r][c4 + 0] = v.x; tile[r][c4 + 1] = v.y;
  tile[r][c4 + 2] = v.z; tile[r][c4 + 3] = v.w;
  __syncthreads();
  ushort4 o;
  o.x = f2bf(tile[c4 + 0][r]); o.y = f2bf(tile[c4 + 1][r]);
  o.z = f2bf(tile[c4 + 2][r]); o.w = f2bf(tile[c4 + 3][r]);
  *(ushort4*)(WT + (size_t)(bn * 32 + r) * K + bk * 32 + c4) = o;
}

// ---------------- concat 3 bias vectors ----------------
__global__ __launch_bounds__(256) void concat3(const float* __restrict__ a,
                                               const float* __restrict__ b,
                                               const float* __restrict__ c,
                                               float* __restrict__ out, int n) {
  int i = blockIdx.x * 256 + threadIdx.x;
  if (i < n) { out[i] = a[i]; out[n + i] = b[i]; out[2 * n + i] = c[i]; }
}

// ---------------- LayerNorm fp32 -> bf16, D=1024, one block per row ----------------
__global__ __launch_bounds__(256) void ln_kernel(const float* __restrict__ x,
                                                 const float* __restrict__ gamma,
                                                 const float* __restrict__ beta,
                                                 u16* __restrict__ out) {
  const int row = blockIdx.x;
  const int tid = threadIdx.x;
  const float4 v = *(const float4*)(x + (size_t)row * 1024 + tid * 4);
  float s = v.x + v.y + v.z + v.w;
  float s2 = v.x * v.x + v.y * v.y + v.z * v.z + v.w * v.w;
#pragma unroll
  for (int m = 1; m < 64; m <<= 1) {
    s += __shfl_xor(s, m, 64);
    s2 += __shfl_xor(s2, m, 64);
  }
  __shared__ float red[8];
  const int w = tid >> 6;
  if ((tid & 63) == 0) { red[w] = s; red[4 + w] = s2; }
  __syncthreads();
  s = red[0] + red[1] + red[2] + red[3];
  s2 = red[4] + red[5] + red[6] + red[7];
  const float mean = s * (1.0f / 1024.0f);
  const float var = s2 * (1.0f / 1024.0f) - mean * mean;
  const float rstd = rsqrtf(var + 1e-5f);
  const float4 g = *(const float4*)(gamma + tid * 4);
  const float4 b = *(const float4*)(beta + tid * 4);
  ushort4 o;
  o.x = f2bf(g.x * (v.x - mean) * rstd + b.x);
  o.y = f2bf(g.y * (v.y - mean) * rstd + b.y);
  o.z = f2bf(g.z * (v.z - mean) * rstd + b.z);
  o.w = f2bf(g.w * (v.w - mean) * rstd + b.w);
  *(ushort4*)(out + (size_t)row * 1024 + tid * 4) = o;
}

// ---------------- GEMM: C[M,N] = A[M,K](bf16) @ BT[N,K](bf16)^T + epilogue ----------------
// EPI 0: out bf16 = acc + bias
// EPI 1: out f32  = acc + bias + res
// EPI 2: out bf16 = gelu_erf(acc + bias)
// BN: 128 (2x2 waves, 4x4 frags) or 64 (4x1 waves, 2x4 frags)
template <int EPI, int BN>
__global__ __launch_bounds__(256, 2) void gemm_bt(const u16* __restrict__ A,
                                                  const u16* __restrict__ BT,
                                                  const float* __restrict__ bias,
                                                  const float* __restrict__ res,
                                                  void* __restrict__ outp,
                                                  int M, int N, int K) {
  constexpr int MF = (BN == 128) ? 4 : 2;   // 16-row frags per wave
  constexpr int BCH = BN / 64;              // B staging chunks per thread
  __shared__ __align__(16) u16 As[128 * 32];
  __shared__ __align__(16) u16 Bs[BN * 32];
  const int nBN = N / BN;
  const int bm = blockIdx.x / nBN;
  const int bn = blockIdx.x % nBN;
  const int tid = threadIdx.x;
  const int lane = tid & 63;
  const int wid = tid >> 6;
  const int wm = (BN == 128) ? (wid >> 1) : wid;
  const int wn = (BN == 128) ? (wid & 1) : 0;

  int aoffs[MF], boffs[4];
#pragma unroll
  for (int m = 0; m < MF; ++m) {
    int rowa = wm * (MF * 16) + m * 16 + (lane & 15);
    aoffs[m] = rowa * 32 + (((lane >> 4) ^ ((rowa >> 1) & 3)) << 3);
  }
#pragma unroll
  for (int n = 0; n < 4; ++n) {
    int rowb = wn * 64 + n * 16 + (lane & 15);
    boffs[n] = rowb * 32 + (((lane >> 4) ^ ((rowb >> 1) & 3)) << 3);
  }

  size_t ga[2], gb[BCH];
  int loa[2], lob[BCH];
#pragma unroll
  for (int c = 0; c < 2; ++c) {
    int idx = tid + (c << 8);
    int row = idx >> 2;
    int gch = (idx & 3) ^ ((row >> 1) & 3);
    ga[c] = (size_t)(bm * 128 + row) * K + (gch << 3);
    loa[c] = idx << 4;
  }
#pragma unroll
  for (int c = 0; c < BCH; ++c) {
    int idx = tid + (c << 8);
    int row = idx >> 2;
    int gch = (idx & 3) ^ ((row >> 1) & 3);
    gb[c] = (size_t)(bn * BN + row) * K + (gch << 3);
    lob[c] = idx << 4;
  }

  f32x4 acc[MF][4] = {};

  for (int k0 = 0; k0 < K; k0 += 32) {
    __syncthreads();
#pragma unroll
    for (int c = 0; c < 2; ++c) GLOAD16(A + ga[c] + k0, (char*)As + loa[c]);
#pragma unroll
    for (int c = 0; c < BCH; ++c) GLOAD16(BT + gb[c] + k0, (char*)Bs + lob[c]);
    __syncthreads();
    bf16x8 af[MF], bfr[4];
#pragma unroll
    for (int m = 0; m < MF; ++m) af[m] = *(const bf16x8*)(As + aoffs[m]);
#pragma unroll
    for (int n = 0; n < 4; ++n) bfr[n] = *(const bf16x8*)(Bs + boffs[n]);
#pragma unroll
    for (int m = 0; m < MF; ++m)
#pragma unroll
      for (int n = 0; n < 4; ++n)
        acc[m][n] = __builtin_amdgcn_mfma_f32_16x16x32_bf16(af[m], bfr[n], acc[m][n], 0, 0, 0);
  }

  const int rbase = bm * 128 + wm * (MF * 16);
  const int cbase = bn * BN + wn * 64;
#pragma unroll
  for (int m = 0; m < MF; ++m) {
#pragma unroll
    for (int n = 0; n < 4; ++n) {
      const int col = cbase + n * 16 + (lane & 15);
      const int row0 = rbase + m * 16 + ((lane >> 4) << 2);
      const float bv = bias[col];
#pragma unroll
      for (int r = 0; r < 4; ++r) {
        const int row = row0 + r;
        float v = acc[m][n][r] + bv;
        if (EPI == 1) {
          ((float*)outp)[(size_t)row * N + col] = v + res[(size_t)row * N + col];
        } else if (EPI == 2) {
          v = 0.5f * v * (1.0f + erff(v * 0.70710678118654752f));
          ((u16*)outp)[(size_t)row * N + col] = f2bf(v);
        } else {
          ((u16*)outp)[(size_t)row * N + col] = f2bf(v);
        }
      }
    }
  }
}

// ---------------- causal flash attention, T=2048, H=16, Dh=64 ----------------
// QKV merged: bf16 (B*T, 3072): Q at col 0, K at 1024, V at 2048 (+h*64).
// Paired q-tiles: block handles q-tiles (pr, 31-pr); waves 0-3 -> pr, waves 4-7 -> 31-pr.
// Double-buffered K (global_load_lds) and V (reg-staged transpose).
__global__ __launch_bounds__(512, 4) void attn_kernel(const u16* __restrict__ QKV,
                                                      u16* __restrict__ O) {
  __shared__ __align__(16) u16 Ks[2][64 * 64];
  __shared__ __align__(16) u16 Vt[2][64 * 64];
  __shared__ __align__(16) u16 Ps[128 * 64];
  const int T = 2048, LD = 3072, OLD = 1024;
  const int pr = blockIdx.x & 15;
  const int bh = blockIdx.x >> 4;
  const int b = bh >> 4, h = bh & 15;
  const int tid = threadIdx.x;
  const int lane = tid & 63;
  const int w = tid >> 6;                 // 0..7
  const int qt = (w < 4) ? pr : (31 - pr);
  const int nt = 32 - pr;                 // tiles staged (covers larger q-tile)
  const int myNt = qt + 1;                // tiles this wave computes

  const u16* Qb = QKV + (size_t)b * T * LD + h * 64;
  const u16* Kb = Qb + 1024;
  const u16* Vb = Qb + 2048;

  // Q fragments in registers (16-row stripe per wave within its q-tile)
  bf16x8 qf[2];
  const int qrow = qt * 64 + (w & 3) * 16 + (lane & 15);
#pragma unroll
  for (int ks = 0; ks < 2; ++ks)
    qf[ks] = *(const bf16x8*)(Qb + (size_t)qrow * LD + ks * 32 + ((lane >> 4) << 3));

  f32x4 o[4] = {};
  float mrow[4], lrow[4];
#pragma unroll
  for (int r = 0; r < 4; ++r) { mrow[r] = -INFINITY; lrow[r] = 0.0f; }

  // staging constants (512 threads: 1x 16B K gload + 1x bf16x8 V reg load each)
  const int krow = tid >> 3;
  const int kg = ((tid & 7) ^ (krow & 7)) << 3;
  const int vrow = tid >> 3;
  const int vd0 = (tid & 7) << 3;

  // prologue: stage tile 0
  GLOAD16(Kb + (size_t)krow * LD + kg, (char*)&Ks[0][0] + tid * 16);
  {
    bf16x8 vv = *(const bf16x8*)(Vb + (size_t)vrow * LD + vd0);
#pragma unroll
    for (int e = 0; e < 8; ++e) {
      int d = vd0 + e;
      Vt[0][(d << 6) + (vrow ^ ((d & 7) << 3))] = (u16)vv[e];
    }
  }
  __syncthreads();

  int cur = 0;
  for (int j = 0; j < nt; ++j) {
    const bool pre = (j + 1 < nt);
    bf16x8 vv;
    if (pre) {
      GLOAD16(Kb + (size_t)((j + 1) * 64 + krow) * LD + kg, (char*)&Ks[cur ^ 1][0] + tid * 16);
      vv = *(const bf16x8*)(Vb + (size_t)((j + 1) * 64 + vrow) * LD + vd0);
    }

    f32x4 s[4];
    if (j < myNt) {
      // S = Q @ K^T  (16 q-rows x 64 keys per wave)
#pragma unroll
      for (int n = 0; n < 4; ++n) {
        s[n] = (f32x4){0.f, 0.f, 0.f, 0.f};
#pragma unroll
        for (int ks = 0; ks < 2; ++ks) {
          int kr = n * 16 + (lane & 15);
          bf16x8 kf = *(const bf16x8*)(&Ks[cur][0] + (kr << 6) + (((ks * 4 + (lane >> 4)) ^ (kr & 7)) << 3));
          s[n] = __builtin_amdgcn_mfma_f32_16x16x32_bf16(qf[ks], kf, s[n], 0, 0, 0);
        }
      }

      // scale + causal mask + online softmax
      float rmax[4];
#pragma unroll
      for (int r = 0; r < 4; ++r) rmax[r] = -INFINITY;
#pragma unroll
      for (int n = 0; n < 4; ++n) {
#pragma unroll
        for (int r = 0; r < 4; ++r) {
          float sv = s[n][r] * 0.125f;
          if (j == qt) {
            int key = j * 64 + n * 16 + (lane & 15);
            int qg = qt * 64 + (w & 3) * 16 + ((lane >> 4) << 2) + r;
            if (key > qg) sv = -INFINITY;
          }
          s[n][r] = sv;
          rmax[r] = fmaxf(rmax[r], sv);
        }
      }
#pragma unroll
      for (int r = 0; r < 4; ++r) {
        rmax[r] = fmaxf(rmax[r], __shfl_xor(rmax[r], 1, 64));
        rmax[r] = fmaxf(rmax[r], __shfl_xor(rmax[r], 2, 64));
        rmax[r] = fmaxf(rmax[r], __shfl_xor(rmax[r], 4, 64));
        rmax[r] = fmaxf(rmax[r], __shfl_xor(rmax[r], 8, 64));
      }
      float alpha[4];
#pragma unroll
      for (int r = 0; r < 4; ++r) {
        float mn = fmaxf(mrow[r], rmax[r]);
        alpha[r] = __expf(mrow[r] - mn);
        mrow[r] = mn;
      }
      float rsum[4] = {0.f, 0.f, 0.f, 0.f};
#pragma unroll
      for (int n = 0; n < 4; ++n)
#pragma unroll
        for (int r = 0; r < 4; ++r) {
          float p = __expf(s[n][r] - mrow[r]);
          s[n][r] = p;
          rsum[r] += p;
        }
#pragma unroll
      for (int r = 0; r < 4; ++r) {
        rsum[r] += __shfl_xor(rsum[r], 1, 64);
        rsum[r] += __shfl_xor(rsum[r], 2, 64);
        rsum[r] += __shfl_xor(rsum[r], 4, 64);
        rsum[r] += __shfl_xor(rsum[r], 8, 64);
        lrow[r] = lrow[r] * alpha[r] + rsum[r];
#pragma unroll
        for (int df = 0; df < 4; ++df) o[df][r] *= alpha[r];
      }

      // P -> LDS (bf16, swizzled); wave-private rows, no barrier needed
#pragma unroll
      for (int n = 0; n < 4; ++n)
#pragma unroll
        for (int r = 0; r < 4; ++r) {
          int ql = w * 16 + ((lane >> 4) << 2) + r;
          int key = n * 16 + (lane & 15);
          Ps[(ql << 6) + (key ^ ((ql & 7) << 3))] = f2bf(s[n][r]);
        }
    }

    // write next V tile into the other buffer (overlaps with softmax latency)
    if (pre) {
#pragma unroll
      for (int e = 0; e < 8; ++e) {
        int d = vd0 + e;
        Vt[cur ^ 1][(d << 6) + (vrow ^ ((d & 7) << 3))] = (u16)vv[e];
      }
    }

    if (j < myNt) {
      // O += P @ V
#pragma unroll
      for (int ks = 0; ks < 2; ++ks) {
        int qa = w * 16 + (lane & 15);
        bf16x8 pf = *(const bf16x8*)(Ps + (qa << 6) + (((ks * 4 + (lane >> 4)) ^ (qa & 7)) << 3));
#pragma unroll
        for (int df = 0; df < 4; ++df) {
          int dr = df * 16 + (lane & 15);
          bf16x8 vf = *(const bf16x8*)(&Vt[cur][0] + (dr << 6) + (((ks * 4 + (lane >> 4)) ^ (dr & 7)) << 3));
          o[df] = __builtin_amdgcn_mfma_f32_16x16x32_bf16(pf, vf, o[df], 0, 0, 0);
        }
      }
    }
    __syncthreads();
    cur ^= 1;
  }

  // epilogue: O / l
#pragma unroll
  for (int df = 0; df < 4; ++df)
#pragma unroll
    for (int r = 0; r < 4; ++r) {
      int t = qt * 64 + (w & 3) * 16 + ((lane >> 4) << 2) + r;
      int dc = h * 64 + df * 16 + (lane & 15);
      O[(size_t)(b * T + t) * OLD + dc] = f2bf(o[df][r] / lrow[r]);
    }
}

// ---------------- host launch ----------------
extern "C" void kernel_launch(void* const* d_in, const int* in_sizes, int n_in,
                              void* d_out, int out_size, void* d_ws, size_t ws_size,
                              hipStream_t stream) {
  const float* x      = (const float*)d_in[0];
  const float* gamma1 = (const float*)d_in[1];
  const float* beta1  = (const float*)d_in[2];
  const float* Wq     = (const float*)d_in[3];
  const float* bq     = (const float*)d_in[4];
  const float* Wk     = (const float*)d_in[5];
  const float* bk     = (const float*)d_in[6];
  const float* Wv     = (const float*)d_in[7];
  const float* bv     = (const float*)d_in[8];
  const float* Wo     = (const float*)d_in[9];
  const float* bo     = (const float*)d_in[10];
  const float* gamma2 = (const float*)d_in[11];
  const float* beta2  = (const float*)d_in[12];
  const float* W1     = (const float*)d_in[13];
  const float* b1     = (const float*)d_in[14];
  const float* W2     = (const float*)d_in[15];
  const float* b2     = (const float*)d_in[16];

  char* ws = (char*)d_ws;  // 64 MB layout
  u16* WqkvT = (u16*)(ws + 0 * MB);  // 6 MB: WqT | WkT | WvT stacked (rows 0..3071)
  u16* WoT   = (u16*)(ws + 6 * MB);  // 2 MB
  u16* W1T   = (u16*)(ws + 8 * MB);  // 8 MB (4096,1024)
  u16* W2T   = (u16*)(ws + 16 * MB); // 8 MB (1024,4096)
  u16* qkv   = (u16*)(ws + 24 * MB); // 24 MB (4096,3072)
  u16* hb    = (u16*)(ws + 24 * MB); // 32 MB, reuses qkv region after attention
  u16* xn    = (u16*)(ws + 56 * MB); // 8 MB: LN1 out -> attn out -> LN2 out
  float* bqkv = (float*)d_out;       // 12 KB merged bias, d_out dead until O-proj
  float* x1 = (float*)d_out;         // post-attention residual, fp32

  const int M = 4096;  // B*T

  // weights -> bf16 transposed
  twconv<<<dim3(1024), dim3(256), 0, stream>>>(Wq, WqkvT, 1024, 1024);
  twconv<<<dim3(1024), dim3(256), 0, stream>>>(Wk, WqkvT + 1024 * 1024, 1024, 1024);
  twconv<<<dim3(1024), dim3(256), 0, stream>>>(Wv, WqkvT + 2048 * 1024, 1024, 1024);
  twconv<<<dim3(1024), dim3(256), 0, stream>>>(Wo, WoT, 1024, 1024);
  twconv<<<dim3(4096), dim3(256), 0, stream>>>(W1, W1T, 1024, 4096);
  twconv<<<dim3(4096), dim3(256), 0, stream>>>(W2, W2T, 4096, 1024);
  concat3<<<dim3(4), dim3(256), 0, stream>>>(bq, bk, bv, bqkv, 1024);

  // LN1
  ln_kernel<<<dim3(M), dim3(256), 0, stream>>>(x, gamma1, beta1, xn);

  // merged QKV projection: (4096,1024) @ (1024,3072) -> (4096,3072)
  gemm_bt<0, 128><<<dim3(768), dim3(256), 0, stream>>>(xn, WqkvT, bqkv, nullptr, qkv, M, 3072, 1024);

  // attention (paired causal tiles), writes into xn
  attn_kernel<<<dim3(512), dim3(512), 0, stream>>>(qkv, xn);

  // O projection + residual -> x1 (fp32, in d_out)
  gemm_bt<1, 64><<<dim3(512), dim3(256), 0, stream>>>(xn, WoT, bo, x, x1, M, 1024, 1024);

  // LN2
  ln_kernel<<<dim3(M), dim3(256), 0, stream>>>(x1, gamma2, beta2, xn);

  // MLP
  gemm_bt<2, 128><<<dim3(1024), dim3(256), 0, stream>>>(xn, W1T, b1, nullptr, hb, M, 4096, 1024);
  gemm_bt<1, 64><<<dim3(512), dim3(256), 0, stream>>>(hb, W2T, b2, x1, d_out, M, 1024, 4096);
}

// Round 3
// 275.216 us; speedup vs baseline: 1.5749x; 1.1601x over previous
//
#include <hip/hip_runtime.h>
#include <stdint.h>

typedef unsigned short u16;
typedef short bf16x8 __attribute__((ext_vector_type(8)));
typedef float f32x4 __attribute__((ext_vector_type(4)));
typedef float f32x16 __attribute__((ext_vector_type(16)));

#define MB (1024L*1024L)

__device__ inline u16 f2bf(float f) {
  union { float f; unsigned u; } v; v.f = f;
  unsigned r = (v.u + 0x7FFFu + ((v.u >> 16) & 1u)) >> 16;
  return (u16)r;
}

__device__ inline unsigned cvtpk(float lo, float hi) {
  unsigned r;
  asm("v_cvt_pk_bf16_f32 %0, %1, %2" : "=v"(r) : "v"(lo), "v"(hi));
  return r;
}

#define GLOAD16(gptr, lptr) \
  __builtin_amdgcn_global_load_lds((__attribute__((address_space(1))) void*)(gptr), \
                                   (__attribute__((address_space(3))) void*)(lptr), 16, 0, 0)

// ---------------- transpose + convert fp32 (K,N) -> bf16 (N,K) ----------------
__global__ __launch_bounds__(256) void twconv(const float* __restrict__ W,
                                              u16* __restrict__ WT, int K, int N) {
  __shared__ float tile[32][33];
  const int nbn = N >> 5;
  const int bk = blockIdx.x / nbn;
  const int bn = blockIdx.x % nbn;
  const int tid = threadIdx.x;
  const int r = tid >> 3;
  const int c4 = (tid & 7) << 2;
  const float4 v = *(const float4*)(W + (size_t)(bk * 32 + r) * N + bn * 32 + c4);
  tile[r][c4 + 0] = v.x; tile[r][c4 + 1] = v.y;
  tile[r][c4 + 2] = v.z; tile[r][c4 + 3] = v.w;
  __syncthreads();
  ushort4 o;
  o.x = f2bf(tile[c4 + 0][r]); o.y = f2bf(tile[c4 + 1][r]);
  o.z = f2bf(tile[c4 + 2][r]); o.w = f2bf(tile[c4 + 3][r]);
  *(ushort4*)(WT + (size_t)(bn * 32 + r) * K + bk * 32 + c4) = o;
}

// ---------------- concat 3 bias vectors ----------------
__global__ __launch_bounds__(256) void concat3(const float* __restrict__ a,
                                               const float* __restrict__ b,
                                               const float* __restrict__ c,
                                               float* __restrict__ out, int n) {
  int i = blockIdx.x * 256 + threadIdx.x;
  if (i < n) { out[i] = a[i]; out[n + i] = b[i]; out[2 * n + i] = c[i]; }
}

// ---------------- LayerNorm fp32 -> bf16, D=1024, one block per row ----------------
__global__ __launch_bounds__(256) void ln_kernel(const float* __restrict__ x,
                                                 const float* __restrict__ gamma,
                                                 const float* __restrict__ beta,
                                                 u16* __restrict__ out) {
  const int row = blockIdx.x;
  const int tid = threadIdx.x;
  const float4 v = *(const float4*)(x + (size_t)row * 1024 + tid * 4);
  float s = v.x + v.y + v.z + v.w;
  float s2 = v.x * v.x + v.y * v.y + v.z * v.z + v.w * v.w;
#pragma unroll
  for (int m = 1; m < 64; m <<= 1) {
    s += __shfl_xor(s, m, 64);
    s2 += __shfl_xor(s2, m, 64);
  }
  __shared__ float red[8];
  const int w = tid >> 6;
  if ((tid & 63) == 0) { red[w] = s; red[4 + w] = s2; }
  __syncthreads();
  s = red[0] + red[1] + red[2] + red[3];
  s2 = red[4] + red[5] + red[6] + red[7];
  const float mean = s * (1.0f / 1024.0f);
  const float var = s2 * (1.0f / 1024.0f) - mean * mean;
  const float rstd = rsqrtf(var + 1e-5f);
  const float4 g = *(const float4*)(gamma + tid * 4);
  const float4 b = *(const float4*)(beta + tid * 4);
  ushort4 o;
  o.x = f2bf(g.x * (v.x - mean) * rstd + b.x);
  o.y = f2bf(g.y * (v.y - mean) * rstd + b.y);
  o.z = f2bf(g.z * (v.z - mean) * rstd + b.z);
  o.w = f2bf(g.w * (v.w - mean) * rstd + b.w);
  *(ushort4*)(out + (size_t)row * 1024 + tid * 4) = o;
}

// ---------------- GEMM: C[M,N] = A[M,K](bf16) @ BT[N,K](bf16)^T, 2-phase dbuf ----------------
// EPI 0: out bf16 = acc + bias ; 1: out f32 = acc + bias + res ; 2: out bf16 = gelu(acc+bias)
template <int EPI, int BN>
__global__ __launch_bounds__(256, 2) void gemm_bt(const u16* __restrict__ A,
                                                  const u16* __restrict__ BT,
                                                  const float* __restrict__ bias,
                                                  const float* __restrict__ res,
                                                  void* __restrict__ outp,
                                                  int M, int N, int K) {
  constexpr int MF = (BN == 128) ? 4 : 2;
  constexpr int BCH = BN / 64;
  __shared__ __align__(16) u16 As[2][128 * 32];
  __shared__ __align__(16) u16 Bs[2][BN * 32];
  const int nBN = N / BN;
  const int bm = blockIdx.x / nBN;
  const int bn = blockIdx.x % nBN;
  const int tid = threadIdx.x;
  const int lane = tid & 63;
  const int wid = tid >> 6;
  const int wm = (BN == 128) ? (wid >> 1) : wid;
  const int wn = (BN == 128) ? (wid & 1) : 0;

  int aoffs[MF], boffs[4];
#pragma unroll
  for (int m = 0; m < MF; ++m) {
    int rowa = wm * (MF * 16) + m * 16 + (lane & 15);
    aoffs[m] = rowa * 32 + (((lane >> 4) ^ ((rowa >> 1) & 3)) << 3);
  }
#pragma unroll
  for (int n = 0; n < 4; ++n) {
    int rowb = wn * 64 + n * 16 + (lane & 15);
    boffs[n] = rowb * 32 + (((lane >> 4) ^ ((rowb >> 1) & 3)) << 3);
  }

  size_t ga[2], gb[BCH];
  int loa[2], lob[BCH];
#pragma unroll
  for (int c = 0; c < 2; ++c) {
    int idx = tid + (c << 8);
    int row = idx >> 2;
    int gch = (idx & 3) ^ ((row >> 1) & 3);
    ga[c] = (size_t)(bm * 128 + row) * K + (gch << 3);
    loa[c] = idx << 4;
  }
#pragma unroll
  for (int c = 0; c < BCH; ++c) {
    int idx = tid + (c << 8);
    int row = idx >> 2;
    int gch = (idx & 3) ^ ((row >> 1) & 3);
    gb[c] = (size_t)(bn * BN + row) * K + (gch << 3);
    lob[c] = idx << 4;
  }

  f32x4 acc[MF][4] = {};

  // prologue: stage k0=0 into buffer 0
#pragma unroll
  for (int c = 0; c < 2; ++c) GLOAD16(A + ga[c], (char*)As[0] + loa[c]);
#pragma unroll
  for (int c = 0; c < BCH; ++c) GLOAD16(BT + gb[c], (char*)Bs[0] + lob[c]);

  int cur = 0;
  for (int k0 = 0; k0 < K; k0 += 32) {
    __syncthreads();  // publishes buf[cur] (drains staging loads)
    if (k0 + 32 < K) {
#pragma unroll
      for (int c = 0; c < 2; ++c) GLOAD16(A + ga[c] + k0 + 32, (char*)As[cur ^ 1] + loa[c]);
#pragma unroll
      for (int c = 0; c < BCH; ++c) GLOAD16(BT + gb[c] + k0 + 32, (char*)Bs[cur ^ 1] + lob[c]);
    }
    bf16x8 af[MF], bfr[4];
#pragma unroll
    for (int m = 0; m < MF; ++m) af[m] = *(const bf16x8*)(As[cur] + aoffs[m]);
#pragma unroll
    for (int n = 0; n < 4; ++n) bfr[n] = *(const bf16x8*)(Bs[cur] + boffs[n]);
#pragma unroll
    for (int m = 0; m < MF; ++m)
#pragma unroll
      for (int n = 0; n < 4; ++n)
        acc[m][n] = __builtin_amdgcn_mfma_f32_16x16x32_bf16(af[m], bfr[n], acc[m][n], 0, 0, 0);
    cur ^= 1;
  }

  const int rbase = bm * 128 + wm * (MF * 16);
  const int cbase = bn * BN + wn * 64;
#pragma unroll
  for (int m = 0; m < MF; ++m) {
#pragma unroll
    for (int n = 0; n < 4; ++n) {
      const int col = cbase + n * 16 + (lane & 15);
      const int row0 = rbase + m * 16 + ((lane >> 4) << 2);
      const float bv = bias[col];
#pragma unroll
      for (int r = 0; r < 4; ++r) {
        const int row = row0 + r;
        float v = acc[m][n][r] + bv;
        if (EPI == 1) {
          ((float*)outp)[(size_t)row * N + col] = v + res[(size_t)row * N + col];
        } else if (EPI == 2) {
          v = 0.5f * v * (1.0f + erff(v * 0.70710678118654752f));
          ((u16*)outp)[(size_t)row * N + col] = f2bf(v);
        } else {
          ((u16*)outp)[(size_t)row * N + col] = f2bf(v);
        }
      }
    }
  }
}

// ---------------- causal flash attention, 8-warp 32x32 swapped structure ----------------
// QKV merged bf16 (B*T, 3072). T=2048, H=16, Dh=64. Out bf16 (B*T,1024).
// Block: 512 thr; warps 0-3 -> q-chunk cA=p (128 rows), warps 4-7 -> cB=15-p. QBLK=32/warp.
// Swapped QK^T (S^T=K*Q^T, q lane-local) -> in-reg softmax -> cvt_pk+half-swap P^T frags ->
// swapped PV (O^T = V^T * P^T). K via global_load_lds, V reg-staged transpose; both dbuf.
__global__ __launch_bounds__(512, 2) void attn_kernel(const u16* __restrict__ QKV,
                                                      u16* __restrict__ O) {
  __shared__ __align__(16) u16 KV[4][4096];  // K0,K1,V0,V1 (8KB each); reused as Obuf[256][64]
  const int T = 2048, LD = 3072;
  const int p = blockIdx.x & 7;
  const int bh = blockIdx.x >> 3;
  const int b = bh >> 4, hd = bh & 15;
  const int tid = threadIdx.x;
  const int lane = tid & 63;
  const int w = tid >> 6;
  const int h = lane >> 5;
  const int cA = p, cB = 15 - p;
  const int myc = (w < 4) ? cA : cB;
  const int qwb = myc * 128 + (w & 3) * 32;
  const int qg = qwb + (lane & 31);
  const int diag = qwb >> 6;
  const int myNt = diag + 1;
  const int nt = 2 * cB + 2;

  const u16* Qb = QKV + (size_t)b * T * LD + hd * 64;
  const u16* Kb = Qb + 1024;
  const u16* Vb = Qb + 2048;

  // Q fragments in registers: qf[s][j] = Q[qg][16s + 8h + j]
  bf16x8 qf[4];
#pragma unroll
  for (int s = 0; s < 4; ++s)
    qf[s] = *(const bf16x8*)(Qb + (size_t)qg * LD + s * 16 + h * 8);

  f32x16 oacc[2] = {};
  float m = -INFINITY, l = 0.0f;

  // staging geometry (512 threads)
  const int srow = tid >> 3;      // 0..63
  const int scol = tid & 7;       // 16B chunk
  const int kgc = ((scol ^ (srow & 7)) << 3);

  // prologue: stage tile 0
  GLOAD16(Kb + (size_t)srow * LD + kgc, (char*)KV[0] + tid * 16);
  {
    bf16x8 vv0 = *(const bf16x8*)(Vb + (size_t)srow * LD + scol * 8);
#pragma unroll
    for (int e = 0; e < 8; ++e) {
      int d = scol * 8 + e;
      KV[2][(d << 6) | (srow & 7) | ((((srow >> 3) ^ e ^ scol) & 7) << 3)] = (u16)vv0[e];
    }
  }
  __syncthreads();

  int cur = 0;
  for (int j = 0; j < nt; ++j) {
    const bool pre = (j + 1 < nt);
    bf16x8 vv;
    if (pre) {
      GLOAD16(Kb + (size_t)((j + 1) * 64 + srow) * LD + kgc, (char*)KV[cur ^ 1] + tid * 16);
      vv = *(const bf16x8*)(Vb + (size_t)((j + 1) * 64 + srow) * LD + scol * 8);
    }

    if (j < myNt) {
      // S^T = K * Q^T : sacc[t] covers keys 32t..32t+32 (rows), q = lane&31 (cols)
      f32x16 sacc[2] = {};
      const u16* Kp = KV[cur];
#pragma unroll
      for (int t = 0; t < 2; ++t) {
#pragma unroll
        for (int s = 0; s < 4; ++s) {
          int row = t * 32 + (lane & 31);
          bf16x8 kf = *(const bf16x8*)(Kp + (row << 6) + ((((2 * s + h) ^ (row & 7)) & 7) << 3));
          sacc[t] = __builtin_amdgcn_mfma_f32_32x32x16_bf16(kf, qf[s], sacc[t], 0, 0, 0);
        }
      }

      // causal mask (diag tile only)
      if (j == diag) {
#pragma unroll
        for (int t = 0; t < 2; ++t)
#pragma unroll
          for (int r = 0; r < 16; ++r) {
            int key = (j << 6) + 32 * t + (r & 3) + 8 * (r >> 2) + 4 * h;
            if (key > qg) sacc[t][r] = -INFINITY;
          }
      }

      // row max (keys spread over regs + other half)
      float pmax = -INFINITY;
#pragma unroll
      for (int t = 0; t < 2; ++t)
#pragma unroll
        for (int r = 0; r < 16; ++r) pmax = fmaxf(pmax, sacc[t][r]);
      pmax = fmaxf(pmax, __shfl_xor(pmax, 32, 64));

      // defer-max: rescale only when max grew materially (raw scores; *0.125 => p <= e^2)
      if (!__all(pmax - m <= 16.0f)) {
        float mn = fmaxf(m, pmax);
        float alpha = __expf(0.125f * (m - mn));
        m = mn;
        l *= alpha;
#pragma unroll
        for (int d2 = 0; d2 < 2; ++d2)
#pragma unroll
          for (int r = 0; r < 16; ++r) oacc[d2][r] *= alpha;
      }

      // p = exp(0.125*(s-m)), in place; accumulate row sum
      float lsum = 0.0f;
#pragma unroll
      for (int t = 0; t < 2; ++t)
#pragma unroll
        for (int r = 0; r < 16; ++r) {
          float pe = __expf(0.125f * (sacc[t][r] - m));
          sacc[t][r] = pe;
          lsum += pe;
        }
      lsum += __shfl_xor(lsum, 32, 64);
      l += lsum;

      // P^T B-fragments: pf[ks] holds keys 16ks+8h+0..7 for col q (cvt_pk + half swap)
      union PF { unsigned wd[4]; bf16x8 v; } pf[4];
#pragma unroll
      for (int t = 0; t < 2; ++t) {
#pragma unroll
        for (int kb = 0; kb < 2; ++kb) {
          int base = 8 * kb;
          unsigned A0 = cvtpk(sacc[t][base + 0], sacc[t][base + 1]);
          unsigned A2 = cvtpk(sacc[t][base + 2], sacc[t][base + 3]);
          unsigned A4 = cvtpk(sacc[t][base + 4], sacc[t][base + 5]);
          unsigned A6 = cvtpk(sacc[t][base + 6], sacc[t][base + 7]);
          unsigned S0 = (unsigned)__shfl_xor((int)(h ? A0 : A4), 32, 64);
          unsigned S2 = (unsigned)__shfl_xor((int)(h ? A2 : A6), 32, 64);
          PF& u = pf[2 * t + kb];
          u.wd[0] = h ? S0 : A0;
          u.wd[1] = h ? S2 : A2;
          u.wd[2] = h ? A4 : S0;
          u.wd[3] = h ? A6 : S2;
        }
      }

      // O^T += V^T * P^T : oacc[d2] covers d = 32*d2 + crow (rows), q = lane&31 (cols)
      const u16* Vp = KV[2 + cur];
#pragma unroll
      for (int d2 = 0; d2 < 2; ++d2) {
        int d = d2 * 32 + (lane & 31);
#pragma unroll
        for (int ks = 0; ks < 4; ++ks) {
          bf16x8 vf = *(const bf16x8*)(Vp + (d << 6) + ((((2 * ks + h) ^ (d & 7) ^ ((d >> 3) & 7)) & 7) << 3));
          oacc[d2] = __builtin_amdgcn_mfma_f32_32x32x16_bf16(vf, pf[ks].v, oacc[d2], 0, 0, 0);
        }
      }
    }

    // late write of next V tile (load issued early; hides HBM latency under compute)
    if (pre) {
#pragma unroll
      for (int e = 0; e < 8; ++e) {
        int d = scol * 8 + e;
        KV[2 + (cur ^ 1)][(d << 6) | (srow & 7) | ((((srow >> 3) ^ e ^ scol) & 7) << 3)] = (u16)vv[e];
      }
    }
    __syncthreads();
    cur ^= 1;
  }

  // epilogue: O = O^T / l, transpose via LDS, coalesced store
  const float rinv = 1.0f / l;
  u16* Ob = (u16*)KV;
  const int qloc = w * 32 + (lane & 31);
#pragma unroll
  for (int d2 = 0; d2 < 2; ++d2)
#pragma unroll
    for (int r = 0; r < 16; ++r) {
      int d = d2 * 32 + (r & 3) + 8 * (r >> 2) + 4 * h;
      Ob[(qloc << 6) | (d ^ ((qloc & 7) << 3))] = f2bf(oacc[d2][r] * rinv);
    }
  __syncthreads();
#pragma unroll
  for (int it = 0; it < 4; ++it) {
    int r = (tid >> 3) + it * 64;
    int c = tid & 7;
    bf16x8 val = *(const bf16x8*)(Ob + (r << 6) + (((c ^ (r & 7)) & 7) << 3));
    int qg2 = (r < 128) ? (cA * 128 + r) : (cB * 128 + (r - 128));
    *(bf16x8*)(O + (size_t)(b * T + qg2) * 1024 + hd * 64 + c * 8) = val;
  }
}

// ---------------- host launch ----------------
extern "C" void kernel_launch(void* const* d_in, const int* in_sizes, int n_in,
                              void* d_out, int out_size, void* d_ws, size_t ws_size,
                              hipStream_t stream) {
  const float* x      = (const float*)d_in[0];
  const float* gamma1 = (const float*)d_in[1];
  const float* beta1  = (const float*)d_in[2];
  const float* Wq     = (const float*)d_in[3];
  const float* bq     = (const float*)d_in[4];
  const float* Wk     = (const float*)d_in[5];
  const float* bk     = (const float*)d_in[6];
  const float* Wv     = (const float*)d_in[7];
  const float* bv     = (const float*)d_in[8];
  const float* Wo     = (const float*)d_in[9];
  const float* bo     = (const float*)d_in[10];
  const float* gamma2 = (const float*)d_in[11];
  const float* beta2  = (const float*)d_in[12];
  const float* W1     = (const float*)d_in[13];
  const float* b1     = (const float*)d_in[14];
  const float* W2     = (const float*)d_in[15];
  const float* b2     = (const float*)d_in[16];

  char* ws = (char*)d_ws;  // 64 MB layout
  u16* WqkvT = (u16*)(ws + 0 * MB);  // 6 MB: WqT | WkT | WvT (rows 0..3071)
  u16* WoT   = (u16*)(ws + 6 * MB);  // 2 MB
  u16* W1T   = (u16*)(ws + 8 * MB);  // 8 MB (4096,1024)
  u16* W2T   = (u16*)(ws + 16 * MB); // 8 MB (1024,4096)
  u16* qkv   = (u16*)(ws + 24 * MB); // 24 MB (4096,3072)
  u16* hb    = (u16*)(ws + 24 * MB); // 32 MB, reuses qkv region after attention
  u16* xn    = (u16*)(ws + 56 * MB); // 8 MB: LN1 out -> attn out -> LN2 out
  float* bqkv = (float*)d_out;       // merged bias, d_out dead until O-proj
  float* x1 = (float*)d_out;         // post-attention residual, fp32

  const int M = 4096;  // B*T

  twconv<<<dim3(1024), dim3(256), 0, stream>>>(Wq, WqkvT, 1024, 1024);
  twconv<<<dim3(1024), dim3(256), 0, stream>>>(Wk, WqkvT + 1024 * 1024, 1024, 1024);
  twconv<<<dim3(1024), dim3(256), 0, stream>>>(Wv, WqkvT + 2048 * 1024, 1024, 1024);
  twconv<<<dim3(1024), dim3(256), 0, stream>>>(Wo, WoT, 1024, 1024);
  twconv<<<dim3(4096), dim3(256), 0, stream>>>(W1, W1T, 1024, 4096);
  twconv<<<dim3(4096), dim3(256), 0, stream>>>(W2, W2T, 4096, 1024);
  concat3<<<dim3(4), dim3(256), 0, stream>>>(bq, bk, bv, bqkv, 1024);

  ln_kernel<<<dim3(M), dim3(256), 0, stream>>>(x, gamma1, beta1, xn);

  // merged QKV projection
  gemm_bt<0, 128><<<dim3(768), dim3(256), 0, stream>>>(xn, WqkvT, bqkv, nullptr, qkv, M, 3072, 1024);

  // attention
  attn_kernel<<<dim3(256), dim3(512), 0, stream>>>(qkv, xn);

  // O projection + residual -> x1 (fp32, in d_out)
  gemm_bt<1, 64><<<dim3(512), dim3(256), 0, stream>>>(xn, WoT, bo, x, x1, M, 1024, 1024);

  ln_kernel<<<dim3(M), dim3(256), 0, stream>>>(x1, gamma2, beta2, xn);

  // MLP
  gemm_bt<2, 128><<<dim3(1024), dim3(256), 0, stream>>>(xn, W1T, b1, nullptr, hb, M, 4096, 1024);
  gemm_bt<1, 64><<<dim3(512), dim3(256), 0, stream>>>(hb, W2T, b2, x1, d_out, M, 1024, 4096);
}

// Round 4
// 239.533 us; speedup vs baseline: 1.8095x; 1.1490x over previous
//
#include <hip/hip_runtime.h>
#include <stdint.h>

typedef unsigned short u16;
typedef short bf16x8 __attribute__((ext_vector_type(8)));
typedef float f32x4 __attribute__((ext_vector_type(4)));
typedef float f32x16 __attribute__((ext_vector_type(16)));

#define MB (1024L*1024L)

__device__ inline u16 f2bf(float f) {
  union { float f; unsigned u; } v; v.f = f;
  unsigned r = (v.u + 0x7FFFu + ((v.u >> 16) & 1u)) >> 16;
  return (u16)r;
}

__device__ inline unsigned cvtpk(float lo, float hi) {
  unsigned r;
  asm("v_cvt_pk_bf16_f32 %0, %1, %2" : "=v"(r) : "v"(lo), "v"(hi));
  return r;
}

#define GLOAD16(gptr, lptr) \
  __builtin_amdgcn_global_load_lds((__attribute__((address_space(1))) void*)(gptr), \
                                   (__attribute__((address_space(3))) void*)(lptr), 16, 0, 0)

// ---------------- transpose + convert fp32 (K,N) -> bf16 (N,K) ----------------
__global__ __launch_bounds__(256) void twconv(const float* __restrict__ W,
                                              u16* __restrict__ WT, int K, int N) {
  __shared__ float tile[32][33];
  const int nbn = N >> 5;
  const int bk = blockIdx.x / nbn;
  const int bn = blockIdx.x % nbn;
  const int tid = threadIdx.x;
  const int r = tid >> 3;
  const int c4 = (tid & 7) << 2;
  const float4 v = *(const float4*)(W + (size_t)(bk * 32 + r) * N + bn * 32 + c4);
  tile[r][c4 + 0] = v.x; tile[r][c4 + 1] = v.y;
  tile[r][c4 + 2] = v.z; tile[r][c4 + 3] = v.w;
  __syncthreads();
  ushort4 o;
  o.x = f2bf(tile[c4 + 0][r]); o.y = f2bf(tile[c4 + 1][r]);
  o.z = f2bf(tile[c4 + 2][r]); o.w = f2bf(tile[c4 + 3][r]);
  *(ushort4*)(WT + (size_t)(bn * 32 + r) * K + bk * 32 + c4) = o;
}

// ---------------- concat 3 bias vectors ----------------
__global__ __launch_bounds__(256) void concat3(const float* __restrict__ a,
                                               const float* __restrict__ b,
                                               const float* __restrict__ c,
                                               float* __restrict__ out, int n) {
  int i = blockIdx.x * 256 + threadIdx.x;
  if (i < n) { out[i] = a[i]; out[n + i] = b[i]; out[2 * n + i] = c[i]; }
}

// ---------------- LayerNorm fp32 -> bf16, D=1024, one block per row ----------------
__global__ __launch_bounds__(256) void ln_kernel(const float* __restrict__ x,
                                                 const float* __restrict__ gamma,
                                                 const float* __restrict__ beta,
                                                 u16* __restrict__ out) {
  const int row = blockIdx.x;
  const int tid = threadIdx.x;
  const float4 v = *(const float4*)(x + (size_t)row * 1024 + tid * 4);
  float s = v.x + v.y + v.z + v.w;
  float s2 = v.x * v.x + v.y * v.y + v.z * v.z + v.w * v.w;
#pragma unroll
  for (int m = 1; m < 64; m <<= 1) {
    s += __shfl_xor(s, m, 64);
    s2 += __shfl_xor(s2, m, 64);
  }
  __shared__ float red[8];
  const int w = tid >> 6;
  if ((tid & 63) == 0) { red[w] = s; red[4 + w] = s2; }
  __syncthreads();
  s = red[0] + red[1] + red[2] + red[3];
  s2 = red[4] + red[5] + red[6] + red[7];
  const float mean = s * (1.0f / 1024.0f);
  const float var = s2 * (1.0f / 1024.0f) - mean * mean;
  const float rstd = rsqrtf(var + 1e-5f);
  const float4 g = *(const float4*)(gamma + tid * 4);
  const float4 b = *(const float4*)(beta + tid * 4);
  ushort4 o;
  o.x = f2bf(g.x * (v.x - mean) * rstd + b.x);
  o.y = f2bf(g.y * (v.y - mean) * rstd + b.y);
  o.z = f2bf(g.z * (v.z - mean) * rstd + b.z);
  o.w = f2bf(g.w * (v.w - mean) * rstd + b.w);
  *(ushort4*)(out + (size_t)row * 1024 + tid * 4) = o;
}

// ---------------- GEMM: C[M,N] = A[M,K](bf16) @ BT[N,K](bf16)^T ----------------
// BK=64, 2 LDS buffers, depth-2 prefetch, counted vmcnt + raw barriers (T3/T4), setprio (T5).
// EPI 0: out bf16 = acc + bias ; 1: out f32 = acc + bias + res ; 2: out bf16 = gelu(acc+bias)
template <int EPI, int BN>
__global__ __launch_bounds__(256, (BN == 64) ? 3 : 2)
void gemm_bt(const u16* __restrict__ A, const u16* __restrict__ BT,
             const float* __restrict__ bias, const float* __restrict__ res,
             void* __restrict__ outp, int M, int N, int K) {
  constexpr int MF = (BN == 128) ? 4 : 2;   // 16-row A-frags per wave
  constexpr int ACH = 4;                    // A chunks/thread: 128*64*2B/(256*16B)
  constexpr int BCH = BN / 32;              // B chunks/thread (4 or 2)
  constexpr int LOADS = ACH + BCH;          // outstanding loads per staged tile
  __shared__ __align__(16) u16 As[2][128 * 64];
  __shared__ __align__(16) u16 Bs[2][BN * 64];
  const int nBN = N / BN;
  const int bm = blockIdx.x / nBN;
  const int bn = blockIdx.x % nBN;
  const int tid = threadIdx.x;
  const int lane = tid & 63;
  const int wid = tid >> 6;
  const int wm = (BN == 128) ? (wid >> 1) : wid;
  const int wn = (BN == 128) ? (wid & 1) : 0;
  const int e4 = lane >> 4;                 // 0..3 k-subchunk within 32-k group

  // fragment bases (element offsets; row stride 64, chunk = 8 elems, chunk ^= row&7)
  int abase[MF], ax[MF];
#pragma unroll
  for (int m = 0; m < MF; ++m) {
    int rowa = wm * (MF * 16) + m * 16 + (lane & 15);
    abase[m] = rowa * 64; ax[m] = rowa & 7;
  }
  int bbase[4], bx[4];
#pragma unroll
  for (int n = 0; n < 4; ++n) {
    int rowb = wn * 64 + n * 16 + (lane & 15);
    bbase[n] = rowb * 64; bx[n] = rowb & 7;
  }

  // staging: LDS dest linear (idx*16B), global source pre-swizzled (chunk ^= row&7)
  size_t ga[ACH]; int loa[ACH];
#pragma unroll
  for (int c = 0; c < ACH; ++c) {
    int idx = tid + (c << 8);
    int row = idx >> 3;
    int ch = (idx & 7) ^ (row & 7);
    ga[c] = (size_t)(bm * 128 + row) * K + (ch << 3);
    loa[c] = idx << 4;
  }
  size_t gb[BCH]; int lob[BCH];
#pragma unroll
  for (int c = 0; c < BCH; ++c) {
    int idx = tid + (c << 8);
    int row = idx >> 3;
    int ch = (idx & 7) ^ (row & 7);
    gb[c] = (size_t)(bn * BN + row) * K + (ch << 3);
    lob[c] = idx << 4;
  }

#define STAGE_G(t, bb) do { \
  _Pragma("unroll") for (int c = 0; c < ACH; ++c) \
    GLOAD16(A + ga[c] + (size_t)(t) * 64, (char*)As[bb] + loa[c]); \
  _Pragma("unroll") for (int c = 0; c < BCH; ++c) \
    GLOAD16(BT + gb[c] + (size_t)(t) * 64, (char*)Bs[bb] + lob[c]); \
} while (0)

  f32x4 acc[MF][4] = {};
  const int nt = K >> 6;

  STAGE_G(0, 0);
  STAGE_G(1, 1);

  for (int t = 0; t < nt; ++t) {
    if (t + 1 < nt) {
      asm volatile("s_waitcnt vmcnt(%0)" :: "i"(LOADS) : "memory");
    } else {
      asm volatile("s_waitcnt vmcnt(0)" ::: "memory");
    }
    __builtin_amdgcn_s_barrier();          // buf[t&1] published
    const u16* Ap = As[t & 1];
    const u16* Bp = Bs[t & 1];
    bf16x8 af[2][MF], bfr[2][4];
#pragma unroll
    for (int kk = 0; kk < 2; ++kk) {
#pragma unroll
      for (int m = 0; m < MF; ++m)
        af[kk][m] = *(const bf16x8*)(Ap + abase[m] + (((((kk << 2) | e4)) ^ ax[m]) << 3));
#pragma unroll
      for (int n = 0; n < 4; ++n)
        bfr[kk][n] = *(const bf16x8*)(Bp + bbase[n] + (((((kk << 2) | e4)) ^ bx[n]) << 3));
    }
    asm volatile("s_waitcnt lgkmcnt(0)" ::: "memory");
    __builtin_amdgcn_s_barrier();          // all waves done reading buf[t&1]
    if (t + 2 < nt) STAGE_G(t + 2, t & 1);
    __builtin_amdgcn_s_setprio(1);
#pragma unroll
    for (int kk = 0; kk < 2; ++kk)
#pragma unroll
      for (int m = 0; m < MF; ++m)
#pragma unroll
        for (int n = 0; n < 4; ++n)
          acc[m][n] = __builtin_amdgcn_mfma_f32_16x16x32_bf16(af[kk][m], bfr[kk][n], acc[m][n], 0, 0, 0);
    __builtin_amdgcn_s_setprio(0);
  }
#undef STAGE_G

  const int rbase = bm * 128 + wm * (MF * 16);
  const int cbase = bn * BN + wn * 64;
#pragma unroll
  for (int m = 0; m < MF; ++m) {
#pragma unroll
    for (int n = 0; n < 4; ++n) {
      const int col = cbase + n * 16 + (lane & 15);
      const int row0 = rbase + m * 16 + ((lane >> 4) << 2);
      const float bv = bias[col];
#pragma unroll
      for (int r = 0; r < 4; ++r) {
        const int row = row0 + r;
        float v = acc[m][n][r] + bv;
        if (EPI == 1) {
          ((float*)outp)[(size_t)row * N + col] = v + res[(size_t)row * N + col];
        } else if (EPI == 2) {
          float tt = v * (1.0f + 0.044715f * v * v);
          float sg = 1.0f / (1.0f + __expf(-1.5957691216057308f * tt));
          ((u16*)outp)[(size_t)row * N + col] = f2bf(v * sg);
        } else {
          ((u16*)outp)[(size_t)row * N + col] = f2bf(v);
        }
      }
    }
  }
}

// ---------------- causal flash attention, 8-warp 32x32 swapped structure ----------------
// QKV merged bf16 (B*T, 3072). T=2048, H=16, Dh=64. Out bf16 (B*T,1024).
__global__ __launch_bounds__(512, 2) void attn_kernel(const u16* __restrict__ QKV,
                                                      u16* __restrict__ O) {
  __shared__ __align__(16) u16 KV[4][4096];  // K0,K1,V0,V1 (8KB each); reused as Obuf[256][64]
  const int T = 2048, LD = 3072;
  const int p = blockIdx.x & 7;
  const int bh = blockIdx.x >> 3;
  const int b = bh >> 4, hd = bh & 15;
  const int tid = threadIdx.x;
  const int lane = tid & 63;
  const int w = tid >> 6;
  const int h = lane >> 5;
  const int cA = p, cB = 15 - p;
  const int myc = (w < 4) ? cA : cB;
  const int qwb = myc * 128 + (w & 3) * 32;
  const int qg = qwb + (lane & 31);
  const int diag = qwb >> 6;
  const int myNt = diag + 1;
  const int nt = 2 * cB + 2;

  const u16* Qb = QKV + (size_t)b * T * LD + hd * 64;
  const u16* Kb = Qb + 1024;
  const u16* Vb = Qb + 2048;

  bf16x8 qf[4];
#pragma unroll
  for (int s = 0; s < 4; ++s)
    qf[s] = *(const bf16x8*)(Qb + (size_t)qg * LD + s * 16 + h * 8);

  f32x16 oacc[2] = {};
  float m = -INFINITY, l = 0.0f;

  const int srow = tid >> 3;
  const int scol = tid & 7;
  const int kgc = ((scol ^ (srow & 7)) << 3);

  GLOAD16(Kb + (size_t)srow * LD + kgc, (char*)KV[0] + tid * 16);
  {
    bf16x8 vv0 = *(const bf16x8*)(Vb + (size_t)srow * LD + scol * 8);
#pragma unroll
    for (int e = 0; e < 8; ++e) {
      int d = scol * 8 + e;
      KV[2][(d << 6) | (srow & 7) | ((((srow >> 3) ^ e ^ scol) & 7) << 3)] = (u16)vv0[e];
    }
  }
  __syncthreads();

  int cur = 0;
  for (int j = 0; j < nt; ++j) {
    const bool pre = (j + 1 < nt);
    bf16x8 vv;
    if (pre) {
      GLOAD16(Kb + (size_t)((j + 1) * 64 + srow) * LD + kgc, (char*)KV[cur ^ 1] + tid * 16);
      vv = *(const bf16x8*)(Vb + (size_t)((j + 1) * 64 + srow) * LD + scol * 8);
    }

    if (j < myNt) {
      f32x16 sacc[2] = {};
      const u16* Kp = KV[cur];
#pragma unroll
      for (int t = 0; t < 2; ++t) {
#pragma unroll
        for (int s = 0; s < 4; ++s) {
          int row = t * 32 + (lane & 31);
          bf16x8 kf = *(const bf16x8*)(Kp + (row << 6) + ((((2 * s + h) ^ (row & 7)) & 7) << 3));
          sacc[t] = __builtin_amdgcn_mfma_f32_32x32x16_bf16(kf, qf[s], sacc[t], 0, 0, 0);
        }
      }

      if (j == diag) {
#pragma unroll
        for (int t = 0; t < 2; ++t)
#pragma unroll
          for (int r = 0; r < 16; ++r) {
            int key = (j << 6) + 32 * t + (r & 3) + 8 * (r >> 2) + 4 * h;
            if (key > qg) sacc[t][r] = -INFINITY;
          }
      }

      float pmax = -INFINITY;
#pragma unroll
      for (int t = 0; t < 2; ++t)
#pragma unroll
        for (int r = 0; r < 16; ++r) pmax = fmaxf(pmax, sacc[t][r]);
      pmax = fmaxf(pmax, __shfl_xor(pmax, 32, 64));

      if (!__all(pmax - m <= 16.0f)) {
        float mn = fmaxf(m, pmax);
        float alpha = __expf(0.125f * (m - mn));
        m = mn;
        l *= alpha;
#pragma unroll
        for (int d2 = 0; d2 < 2; ++d2)
#pragma unroll
          for (int r = 0; r < 16; ++r) oacc[d2][r] *= alpha;
      }

      float lsum = 0.0f;
#pragma unroll
      for (int t = 0; t < 2; ++t)
#pragma unroll
        for (int r = 0; r < 16; ++r) {
          float pe = __expf(0.125f * (sacc[t][r] - m));
          sacc[t][r] = pe;
          lsum += pe;
        }
      lsum += __shfl_xor(lsum, 32, 64);
      l += lsum;

      union PF { unsigned wd[4]; bf16x8 v; } pf[4];
#pragma unroll
      for (int t = 0; t < 2; ++t) {
#pragma unroll
        for (int kb = 0; kb < 2; ++kb) {
          int base = 8 * kb;
          unsigned A0 = cvtpk(sacc[t][base + 0], sacc[t][base + 1]);
          unsigned A2 = cvtpk(sacc[t][base + 2], sacc[t][base + 3]);
          unsigned A4 = cvtpk(sacc[t][base + 4], sacc[t][base + 5]);
          unsigned A6 = cvtpk(sacc[t][base + 6], sacc[t][base + 7]);
          unsigned S0 = (unsigned)__shfl_xor((int)(h ? A0 : A4), 32, 64);
          unsigned S2 = (unsigned)__shfl_xor((int)(h ? A2 : A6), 32, 64);
          PF& u = pf[2 * t + kb];
          u.wd[0] = h ? S0 : A0;
          u.wd[1] = h ? S2 : A2;
          u.wd[2] = h ? A4 : S0;
          u.wd[3] = h ? A6 : S2;
        }
      }

      const u16* Vp = KV[2 + cur];
#pragma unroll
      for (int d2 = 0; d2 < 2; ++d2) {
        int d = d2 * 32 + (lane & 31);
#pragma unroll
        for (int ks = 0; ks < 4; ++ks) {
          bf16x8 vf = *(const bf16x8*)(Vp + (d << 6) + ((((2 * ks + h) ^ (d & 7) ^ ((d >> 3) & 7)) & 7) << 3));
          oacc[d2] = __builtin_amdgcn_mfma_f32_32x32x16_bf16(vf, pf[ks].v, oacc[d2], 0, 0, 0);
        }
      }
    }

    if (pre) {
#pragma unroll
      for (int e = 0; e < 8; ++e) {
        int d = scol * 8 + e;
        KV[2 + (cur ^ 1)][(d << 6) | (srow & 7) | ((((srow >> 3) ^ e ^ scol) & 7) << 3)] = (u16)vv[e];
      }
    }
    __syncthreads();
    cur ^= 1;
  }

  const float rinv = 1.0f / l;
  u16* Ob = (u16*)KV;
  const int qloc = w * 32 + (lane & 31);
#pragma unroll
  for (int d2 = 0; d2 < 2; ++d2)
#pragma unroll
    for (int r = 0; r < 16; ++r) {
      int d = d2 * 32 + (r & 3) + 8 * (r >> 2) + 4 * h;
      Ob[(qloc << 6) | (d ^ ((qloc & 7) << 3))] = f2bf(oacc[d2][r] * rinv);
    }
  __syncthreads();
#pragma unroll
  for (int it = 0; it < 4; ++it) {
    int r = (tid >> 3) + it * 64;
    int c = tid & 7;
    bf16x8 val = *(const bf16x8*)(Ob + (r << 6) + (((c ^ (r & 7)) & 7) << 3));
    int qg2 = (r < 128) ? (cA * 128 + r) : (cB * 128 + (r - 128));
    *(bf16x8*)(O + (size_t)(b * T + qg2) * 1024 + hd * 64 + c * 8) = val;
  }
}

// ---------------- host launch ----------------
extern "C" void kernel_launch(void* const* d_in, const int* in_sizes, int n_in,
                              void* d_out, int out_size, void* d_ws, size_t ws_size,
                              hipStream_t stream) {
  const float* x      = (const float*)d_in[0];
  const float* gamma1 = (const float*)d_in[1];
  const float* beta1  = (const float*)d_in[2];
  const float* Wq     = (const float*)d_in[3];
  const float* bq     = (const float*)d_in[4];
  const float* Wk     = (const float*)d_in[5];
  const float* bk     = (const float*)d_in[6];
  const float* Wv     = (const float*)d_in[7];
  const float* bv     = (const float*)d_in[8];
  const float* Wo     = (const float*)d_in[9];
  const float* bo     = (const float*)d_in[10];
  const float* gamma2 = (const float*)d_in[11];
  const float* beta2  = (const float*)d_in[12];
  const float* W1     = (const float*)d_in[13];
  const float* b1     = (const float*)d_in[14];
  const float* W2     = (const float*)d_in[15];
  const float* b2     = (const float*)d_in[16];

  char* ws = (char*)d_ws;  // 64 MB layout
  u16* WqkvT = (u16*)(ws + 0 * MB);  // 6 MB
  u16* WoT   = (u16*)(ws + 6 * MB);  // 2 MB
  u16* W1T   = (u16*)(ws + 8 * MB);  // 8 MB (4096,1024)
  u16* W2T   = (u16*)(ws + 16 * MB); // 8 MB (1024,4096)
  u16* qkv   = (u16*)(ws + 24 * MB); // 24 MB (4096,3072)
  u16* hb    = (u16*)(ws + 24 * MB); // 32 MB, reuses qkv region after attention
  u16* xn    = (u16*)(ws + 56 * MB); // 8 MB
  float* bqkv = (float*)d_out;
  float* x1 = (float*)d_out;

  const int M = 4096;

  twconv<<<dim3(1024), dim3(256), 0, stream>>>(Wq, WqkvT, 1024, 1024);
  twconv<<<dim3(1024), dim3(256), 0, stream>>>(Wk, WqkvT + 1024 * 1024, 1024, 1024);
  twconv<<<dim3(1024), dim3(256), 0, stream>>>(Wv, WqkvT + 2048 * 1024, 1024, 1024);
  twconv<<<dim3(1024), dim3(256), 0, stream>>>(Wo, WoT, 1024, 1024);
  twconv<<<dim3(4096), dim3(256), 0, stream>>>(W1, W1T, 1024, 4096);
  twconv<<<dim3(4096), dim3(256), 0, stream>>>(W2, W2T, 4096, 1024);
  concat3<<<dim3(4), dim3(256), 0, stream>>>(bq, bk, bv, bqkv, 1024);

  ln_kernel<<<dim3(M), dim3(256), 0, stream>>>(x, gamma1, beta1, xn);

  gemm_bt<0, 128><<<dim3(768), dim3(256), 0, stream>>>(xn, WqkvT, bqkv, nullptr, qkv, M, 3072, 1024);

  attn_kernel<<<dim3(256), dim3(512), 0, stream>>>(qkv, xn);

  gemm_bt<1, 64><<<dim3(512), dim3(256), 0, stream>>>(xn, WoT, bo, x, x1, M, 1024, 1024);

  ln_kernel<<<dim3(M), dim3(256), 0, stream>>>(x1, gamma2, beta2, xn);

  gemm_bt<2, 128><<<dim3(1024), dim3(256), 0, stream>>>(xn, W1T, b1, nullptr, hb, M, 4096, 1024);
  gemm_bt<1, 64><<<dim3(512), dim3(256), 0, stream>>>(hb, W2T, b2, x1, d_out, M, 1024, 4096);
}